// Round 15
// baseline (131.541 us; speedup 1.0000x reference)
//
#include <hip/hip_runtime.h>
#include <hip/hip_bf16.h>
#include <math.h>

#define SEQ 2048
#define NH  16
#define DKH 64
#define DM  1024
#define MR  4096   // BATCH*SEQ

using bf16x8 = __attribute__((ext_vector_type(8))) short;
using f32x4  = __attribute__((ext_vector_type(4))) float;

__device__ __forceinline__ ushort f2b(float f) {
  unsigned u = __float_as_uint(f);
  return (ushort)((u + 0x7fffu + ((u >> 16) & 1u)) >> 16);
}

__device__ __forceinline__ float exp2_fast(float x) {
  float r; asm("v_exp_f32 %0, %1" : "=v"(r) : "v"(x)); return r;
}

// packed bf16 pair via compiler intrinsic (correct hazards/scheduling)
__device__ __forceinline__ unsigned cvt_pk(float lo, float hi) {
  __hip_bfloat162 h = __float22bfloat162_rn(float2{lo, hi});
  return *reinterpret_cast<unsigned*>(&h);
}

__device__ __forceinline__ void gll16(const void* g, void* l) {
  __builtin_amdgcn_global_load_lds(
      (const __attribute__((address_space(1))) void*)g,
      (__attribute__((address_space(3))) void*)l, 16, 0, 0);
}

// ---------------------------------------------------------------------------
// fp32 -> bf16 conversion of x and the 4 weight matrices (one launch)
// ---------------------------------------------------------------------------
__global__ __launch_bounds__(256) void cvt_all(
    const float* __restrict__ x,  const float* __restrict__ wq,
    const float* __restrict__ wk, const float* __restrict__ wv,
    const float* __restrict__ wo,
    ushort* __restrict__ xb,  ushort* __restrict__ wqb, ushort* __restrict__ wkb,
    ushort* __restrict__ wvb, ushort* __restrict__ wob)
{
  size_t e = ((size_t)blockIdx.x * 256 + threadIdx.x) * 4;
  const float* s; ushort* d; size_t off;
  if      (e < 4194304) { s = x;  d = xb;  off = e; }
  else if (e < 5242880) { s = wq; d = wqb; off = e - 4194304; }
  else if (e < 6291456) { s = wk; d = wkb; off = e - 5242880; }
  else if (e < 7340032) { s = wv; d = wvb; off = e - 6291456; }
  else                  { s = wo; d = wob; off = e - 7340032; }
  float4 f = *(const float4*)(s + off);
  ushort4 o4 = { f2b(f.x), f2b(f.y), f2b(f.z), f2b(f.w) };
  *(ushort4*)(d + off) = o4;
}

// ---------------------------------------------------------------------------
// Fused QKV projection (unchanged; Q pre-scale 0.125*log2(e)).
// ---------------------------------------------------------------------------
__global__ __launch_bounds__(512) void gemm_qkv(
    const ushort* __restrict__ X,
    const ushort* __restrict__ Wq, const ushort* __restrict__ Wk, const ushort* __restrict__ Wv,
    ushort* __restrict__ Q, ushort* __restrict__ K, ushort* __restrict__ Vt,
    const int* __restrict__ pos)
{
  __shared__ __align__(16) char As[2][16384];
  __shared__ __align__(16) char Bs[2][16384];

  const int id  = blockIdx.x;          // 768 blocks
  const int xcd = id & 7;
  const int i   = id >> 3;             // 0..95
  const int mt  = xcd * 4 + (i & 3);   // 0..31
  const int nt  = i >> 2;              // 0..23
  const int m0  = mt * 128;
  const int nG  = nt * 128;
  const int z   = nG >> 10;            // 0:Q 1:K 2:V
  const int n0  = nG & 1023;
  const ushort* W = (z == 0) ? Wq : (z == 1) ? Wk : Wv;

  const int tid  = threadIdx.x;
  const int lane = tid & 63;
  const int w    = tid >> 6;           // 0..7
  const int wm   = (w >> 2) * 64;
  const int wn   = (w & 3) * 32;
  const int li   = lane & 15;
  const int g    = lane >> 4;

  f32x4 acc[4][2] = {};

  auto stage = [&](int t, int buf) {
    const int k0 = t * 64;
    #pragma unroll
    for (int it = 0; it < 2; ++it) {
      const int L  = w * 2048 + it * 1024 + lane * 16;
      const int r  = L >> 7;
      const int sc = ((L >> 4) & 7) ^ (r & 7);
      gll16(X + (size_t)(m0 + r) * DM + k0 + sc * 8, &As[buf][w * 2048 + it * 1024]);
      gll16(W + (size_t)(n0 + r) * DM + k0 + sc * 8, &Bs[buf][w * 2048 + it * 1024]);
    }
  };

  auto compute = [&](int buf) {
    #pragma unroll
    for (int ks = 0; ks < 2; ++ks) {
      bf16x8 af[4], bfr[2];
      #pragma unroll
      for (int mf = 0; mf < 4; ++mf) {
        const int row = wm + mf * 16 + li;
        af[mf] = *(const bf16x8*)(&As[buf][row * 128 + (((ks * 4 + g) ^ (row & 7)) << 4)]);
      }
      #pragma unroll
      for (int nf = 0; nf < 2; ++nf) {
        const int row = wn + nf * 16 + li;
        bfr[nf] = *(const bf16x8*)(&Bs[buf][row * 128 + (((ks * 4 + g) ^ (row & 7)) << 4)]);
      }
      #pragma unroll
      for (int mf = 0; mf < 4; ++mf)
        #pragma unroll
        for (int nf = 0; nf < 2; ++nf)
          acc[mf][nf] = __builtin_amdgcn_mfma_f32_16x16x32_bf16(af[mf], bfr[nf], acc[mf][nf], 0, 0, 0);
    }
  };

  stage(0, 0);
  for (int t = 0; t < 16; ++t) {
    if (t < 15) {
      stage(t + 1, (t + 1) & 1);
      __builtin_amdgcn_sched_barrier(0);
      asm volatile("s_waitcnt vmcnt(4)" ::: "memory");
    } else {
      asm volatile("s_waitcnt vmcnt(0)" ::: "memory");
    }
    __builtin_amdgcn_s_barrier();
    __builtin_amdgcn_sched_barrier(0);
    compute(t & 1);
    __builtin_amdgcn_sched_barrier(0);
    __builtin_amdgcn_s_barrier();
  }

  #pragma unroll
  for (int nf = 0; nf < 2; ++nf) {
    const int n = n0 + wn + nf * 16 + li;
    const int h = n >> 6;
    const int d = n & 63;
    if (z == 2) {
      #pragma unroll
      for (int mf = 0; mf < 4; ++mf) {
        const int m  = m0 + wm + mf * 16 + g * 4;
        const int b  = m >> 11;
        const int s2 = m & (SEQ - 1);
        ushort4 pk = { f2b(acc[mf][nf][0]), f2b(acc[mf][nf][1]),
                       f2b(acc[mf][nf][2]), f2b(acc[mf][nf][3]) };
        *(ushort4*)(Vt + (((size_t)b * NH + h) * DKH + d) * SEQ + s2) = pk;
      }
    } else {
      ushort* DST = (z == 0) ? Q : K;
      const float freq = __expf(-(float)(d >> 1) * 0.2878231366242557f);
      #pragma unroll
      for (int mf = 0; mf < 4; ++mf) {
        #pragma unroll
        for (int r = 0; r < 4; ++r) {
          const int m  = m0 + wm + mf * 16 + g * 4 + r;
          const int b  = m >> 11;
          const int s2 = m & (SEQ - 1);
          const float ang = (float)pos[s2] * freq;
          float sn, cs;
          __sincosf(ang, &sn, &cs);
          const float v1 = acc[mf][nf][r];
          const float v2 = __shfl_xor(v1, 1);
          float ov = (d & 1) ? (v2 * sn + v1 * cs)
                             : (v1 * cs - v2 * sn);
          if (z == 0) ov *= 0.1803368801111204f;   // 0.125 * log2(e)
          DST[(((size_t)b * NH + h) * SEQ + s2) * DKH + d] = f2b(ov);
        }
      }
    }
  }
}

// ---------------------------------------------------------------------------
// Wo projection (unchanged).
// ---------------------------------------------------------------------------
__global__ __launch_bounds__(512) void gemm_wo(
    const ushort* __restrict__ A, const ushort* __restrict__ W,
    float* __restrict__ out)
{
  __shared__ __align__(16) char As[2][16384];
  __shared__ __align__(16) char Bs[2][16384];

  const int id  = blockIdx.x;          // 256 blocks
  const int xcd = id & 7;
  const int i   = id >> 3;
  const int mt  = xcd * 4 + (i & 3);
  const int nt  = i >> 2;
  const int m0  = mt * 128;
  const int n0  = nt * 128;

  const int tid  = threadIdx.x;
  const int lane = tid & 63;
  const int w    = tid >> 6;
  const int wm   = (w >> 2) * 64;
  const int wn   = (w & 3) * 32;
  const int li   = lane & 15;
  const int g    = lane >> 4;

  f32x4 acc[4][2] = {};

  auto stage = [&](int t, int buf) {
    const int k0 = t * 64;
    #pragma unroll
    for (int it = 0; it < 2; ++it) {
      const int L  = w * 2048 + it * 1024 + lane * 16;
      const int r  = L >> 7;
      const int sc = ((L >> 4) & 7) ^ (r & 7);
      gll16(A + (size_t)(m0 + r) * DM + k0 + sc * 8, &As[buf][w * 2048 + it * 1024]);
      gll16(W + (size_t)(n0 + r) * DM + k0 + sc * 8, &Bs[buf][w * 2048 + it * 1024]);
    }
  };

  auto compute = [&](int buf) {
    #pragma unroll
    for (int ks = 0; ks < 2; ++ks) {
      bf16x8 af[4], bfr[2];
      #pragma unroll
      for (int mf = 0; mf < 4; ++mf) {
        const int row = wm + mf * 16 + li;
        af[mf] = *(const bf16x8*)(&As[buf][row * 128 + (((ks * 4 + g) ^ (row & 7)) << 4)]);
      }
      #pragma unroll
      for (int nf = 0; nf < 2; ++nf) {
        const int row = wn + nf * 16 + li;
        bfr[nf] = *(const bf16x8*)(&Bs[buf][row * 128 + (((ks * 4 + g) ^ (row & 7)) << 4)]);
      }
      #pragma unroll
      for (int mf = 0; mf < 4; ++mf)
        #pragma unroll
        for (int nf = 0; nf < 2; ++nf)
          acc[mf][nf] = __builtin_amdgcn_mfma_f32_16x16x32_bf16(af[mf], bfr[nf], acc[mf][nf], 0, 0, 0);
    }
  };

  stage(0, 0);
  for (int t = 0; t < 16; ++t) {
    if (t < 15) {
      stage(t + 1, (t + 1) & 1);
      __builtin_amdgcn_sched_barrier(0);
      asm volatile("s_waitcnt vmcnt(4)" ::: "memory");
    } else {
      asm volatile("s_waitcnt vmcnt(0)" ::: "memory");
    }
    __builtin_amdgcn_s_barrier();
    __builtin_amdgcn_sched_barrier(0);
    compute(t & 1);
    __builtin_amdgcn_sched_barrier(0);
    __builtin_amdgcn_s_barrier();
  }

  #pragma unroll
  for (int nf = 0; nf < 2; ++nf)
    #pragma unroll
    for (int mf = 0; mf < 4; ++mf)
      #pragma unroll
      for (int r = 0; r < 4; ++r)
        out[(size_t)(m0 + wm + mf * 16 + g * 4 + r) * DM + n0 + wn + nf * 16 + li] = acc[mf][nf][r];
}

// ---------------------------------------------------------------------------
// Causal flash attention — r13 math, but 32 q-rows PER WAVE (two 16-row
// fragments f=0,1) and 2-wave blocks. Each K/V fragment is read from LDS
// ONCE and feeds TWO MFMAs (one per q-fragment) -> LDS-read traffic per
// block-trip halves (64KB -> 32KB); staging/frag address VALU amortized 2x;
// barrier scope = 2 waves. Grid 1024 blocks (24KB LDS -> 6 blocks/CU).
// 16x16 swapped QK^T, lane-local softmax, exp2 domain, defer-max, diag-only
// mask, cvt_pk P-pack, complementary heavy-first mapping — all unchanged.
// ---------------------------------------------------------------------------
__global__ __launch_bounds__(128) void attn(
    const ushort* __restrict__ Q, const ushort* __restrict__ K,
    const ushort* __restrict__ Vt, ushort* __restrict__ AO)
{
  __shared__ __align__(16) char Ks[8192];   // 64 kv-rows x 128B, swizzled
  __shared__ __align__(16) char Vs[8192];   // 64 d-rows x 128B, swizzled
  __shared__ __align__(16) char Ps[8192];   // 2 waves x 2 frags x 2KB

  const int tid  = threadIdx.x;
  const int lane = tid & 63;
  const int w    = tid >> 6;           // 0..1
  const int li   = lane & 15;
  const int g    = lane >> 4;

  const int bx  = blockIdx.x;          // 1024 blocks
  const int xcd = bx & 7;
  const int idx = bx >> 3;             // 0..127
  const int j   = idx >> 2;            // 0..31
  const int s   = idx & 3;
  const int qb  = (s & 1) ? (31 - j) : j;   // complementary pairing
  const int bh  = s * 8 + xcd;
  const int q0b = qb * 64;
  const int n   = qb + 1;              // kv64 tiles
  const int q0w = q0b + w * 32;        // wave's 32 q-rows

  const ushort* Qb = Q  + (size_t)bh * SEQ * DKH;
  const ushort* Kb = K  + (size_t)bh * SEQ * DKH;
  const ushort* Vb = Vt + (size_t)bh * DKH * SEQ;

  // Q B-frags for both 16-row fragments (f=0,1)
  bf16x8 qfA[2], qfB[2];
  #pragma unroll
  for (int f = 0; f < 2; ++f) {
    const ushort* qr = Qb + (size_t)(q0w + f * 16 + li) * DKH;
    qfA[f] = *(const bf16x8*)(qr + g * 8);
    qfB[f] = *(const bf16x8*)(qr + 32 + g * 8);
  }

  f32x4 o[2][4] = {};
  float m_[2] = { -INFINITY, -INFINITY };
  float l_[2] = { 0.f, 0.f };

  auto stage = [&](int kt) {           // 2 waves stage 16KB (8 gll16 each)
    const int k0 = kt * 64;
    #pragma unroll
    for (int it = 0; it < 4; ++it) {
      const int L  = w * 4096 + it * 1024 + lane * 16;
      const int r  = L >> 7;
      const int sc = ((L >> 4) & 7) ^ (r & 7);
      gll16(Kb + (size_t)(k0 + r) * DKH + sc * 8, Ks + w * 4096 + it * 1024);
      gll16(Vb + (size_t)r * SEQ + k0 + sc * 8,   Vs + w * 4096 + it * 1024);
    }
  };

  auto computeT = [&](int t, bool diag) {
    const int k0 = t * 64;

    // S^T = K Q^T for both q-fragments; each K-frag read feeds 2 MFMAs
    f32x4 st[2][4] = {};
    __builtin_amdgcn_s_setprio(1);
    #pragma unroll
    for (int nf = 0; nf < 4; ++nf) {
      const int row = nf * 16 + li;
      bf16x8 kfa = *(const bf16x8*)(Ks + row * 128 + (((0 + g) ^ (row & 7)) << 4));
      bf16x8 kfb = *(const bf16x8*)(Ks + row * 128 + (((4 + g) ^ (row & 7)) << 4));
      st[0][nf] = __builtin_amdgcn_mfma_f32_16x16x32_bf16(kfa, qfA[0], st[0][nf], 0, 0, 0);
      st[0][nf] = __builtin_amdgcn_mfma_f32_16x16x32_bf16(kfb, qfB[0], st[0][nf], 0, 0, 0);
      st[1][nf] = __builtin_amdgcn_mfma_f32_16x16x32_bf16(kfa, qfA[1], st[1][nf], 0, 0, 0);
      st[1][nf] = __builtin_amdgcn_mfma_f32_16x16x32_bf16(kfb, qfB[1], st[1][nf], 0, 0, 0);
    }
    __builtin_amdgcn_s_setprio(0);

    bf16x8 pf0[2], pf1[2];
    #pragma unroll
    for (int f = 0; f < 2; ++f) {
      const int q0f = q0w + f * 16;

      if (diag) {                      // mask only bites on the diagonal tile
        #pragma unroll
        for (int nf = 0; nf < 4; ++nf)
          #pragma unroll
          for (int r = 0; r < 4; ++r)
            if (k0 + nf * 16 + g * 4 + r > q0f + li) st[f][nf][r] = -1e30f;
      }

      // lane-local row max (row q = q0f + li)
      float mx = fmaxf(fmaxf(fmaxf(st[f][0][0], st[f][0][1]), fmaxf(st[f][0][2], st[f][0][3])),
                       fmaxf(fmaxf(st[f][1][0], st[f][1][1]), fmaxf(st[f][1][2], st[f][1][3])));
      mx = fmaxf(mx, fmaxf(fmaxf(fmaxf(st[f][2][0], st[f][2][1]), fmaxf(st[f][2][2], st[f][2][3])),
                           fmaxf(fmaxf(st[f][3][0], st[f][3][1]), fmaxf(st[f][3][2], st[f][3][3]))));
      mx = fmaxf(mx, __shfl_xor(mx, 16));
      mx = fmaxf(mx, __shfl_xor(mx, 32));

      const bool rescale = !__all(mx - m_[f] <= 8.0f);   // defer-max
      float al = 1.0f;
      if (rescale) {
        const float newm = fmaxf(m_[f], mx);
        al = exp2_fast(m_[f] - newm);
        m_[f] = newm;
      }

      float p[4][4];
      float rs = 0.f;
      #pragma unroll
      for (int nf = 0; nf < 4; ++nf)
        #pragma unroll
        for (int r = 0; r < 4; ++r) {
          p[nf][r] = exp2_fast(st[f][nf][r] - m_[f]);
          rs += p[nf][r];
        }
      rs += __shfl_xor(rs, 16);
      rs += __shfl_xor(rs, 32);

      if (rescale) {
        l_[f] = l_[f] * al + rs;
        float alr[4];
        #pragma unroll
        for (int r = 0; r < 4; ++r) alr[r] = __shfl(al, g * 4 + r);
        #pragma unroll
        for (int nf = 0; nf < 4; ++nf)
          #pragma unroll
          for (int r = 0; r < 4; ++r) o[f][nf][r] *= alr[r];
      } else {
        l_[f] += rs;
      }

      // P -> wave-private LDS rows (transpose to A-frag layout)
      char* Pw = Ps + w * 4096 + f * 2048;
      #pragma unroll
      for (int nf = 0; nf < 4; ++nf) {
        uint2 pv = { cvt_pk(p[nf][0], p[nf][1]), cvt_pk(p[nf][2], p[nf][3]) };
        const int cw = nf * 2 + (g >> 1);
        *(uint2*)(Pw + li * 128 + ((cw ^ (li & 7)) << 4) + ((g & 1) << 3)) = pv;
      }
      pf0[f] = *(const bf16x8*)(Pw + li * 128 + (((0 + g) ^ (li & 7)) << 4));
      pf1[f] = *(const bf16x8*)(Pw + li * 128 + (((4 + g) ^ (li & 7)) << 4));
    }

    // O += P V ; each V-frag read feeds 2 MFMAs
    __builtin_amdgcn_s_setprio(1);
    #pragma unroll
    for (int nf = 0; nf < 4; ++nf) {
      const int row = nf * 16 + li;
      bf16x8 vfa = *(const bf16x8*)(Vs + row * 128 + (((0 + g) ^ (row & 7)) << 4));
      bf16x8 vfb = *(const bf16x8*)(Vs + row * 128 + (((4 + g) ^ (row & 7)) << 4));
      o[0][nf] = __builtin_amdgcn_mfma_f32_16x16x32_bf16(pf0[0], vfa, o[0][nf], 0, 0, 0);
      o[0][nf] = __builtin_amdgcn_mfma_f32_16x16x32_bf16(pf1[0], vfb, o[0][nf], 0, 0, 0);
      o[1][nf] = __builtin_amdgcn_mfma_f32_16x16x32_bf16(pf0[1], vfa, o[1][nf], 0, 0, 0);
      o[1][nf] = __builtin_amdgcn_mfma_f32_16x16x32_bf16(pf1[1], vfb, o[1][nf], 0, 0, 0);
    }
    __builtin_amdgcn_s_setprio(0);
  };

  // ---- single-buffered loop; TLP across ~6 resident blocks hides stalls ----
  for (int t = 0; t < n; ++t) {
    stage(t);
    __syncthreads();                   // drains vmcnt; staged tile visible
    computeT(t, t == n - 1);
    __syncthreads();                   // all reads done before restage
  }

  // epilogue per fragment
  const int b = bh >> 4, hh = bh & 15;
  #pragma unroll
  for (int f = 0; f < 2; ++f) {
    const float inv = 1.0f / l_[f];
    float ir[4];
    #pragma unroll
    for (int r = 0; r < 4; ++r) ir[r] = __shfl(inv, g * 4 + r);
    #pragma unroll
    for (int nf = 0; nf < 4; ++nf)
      #pragma unroll
      for (int r = 0; r < 4; ++r) {
        const int q = q0w + f * 16 + g * 4 + r;
        AO[((size_t)b * SEQ + q) * DM + hh * DKH + nf * 16 + li] = f2b(o[f][nf][r] * ir[r]);
      }
  }
}

// ---------------------------------------------------------------------------
extern "C" void kernel_launch(void* const* d_in, const int* in_sizes, int n_in,
                              void* d_out, int out_size, void* d_ws, size_t ws_size,
                              hipStream_t stream)
{
  const float* x   = (const float*)d_in[0];
  const int*   pos = (const int*)  d_in[1];
  const float* Wq  = (const float*)d_in[2];
  const float* Wk  = (const float*)d_in[3];
  const float* Wv  = (const float*)d_in[4];
  const float* Wo  = (const float*)d_in[5];
  float* out = (float*)d_out;

  ushort* ws  = (ushort*)d_ws;
  ushort* xb  = ws;                    // 4M
  ushort* wqb = xb  + 4194304;         // 1M each
  ushort* wkb = wqb + 1048576;
  ushort* wvb = wkb + 1048576;
  ushort* wob = wvb + 1048576;
  ushort* Qb  = wob + 1048576;         // 4M each
  ushort* Kb  = Qb  + 4194304;
  ushort* Vtb = Kb  + 4194304;
  ushort* AOb = Vtb + 4194304;

  cvt_all<<<8192, 256, 0, stream>>>(x, Wq, Wk, Wv, Wo, xb, wqb, wkb, wvb, wob);
  gemm_qkv<<<768, 512, 0, stream>>>(xb, wqb, wkb, wvb, Qb, Kb, Vtb, pos);
  attn<<<1024, 128, 0, stream>>>(Qb, Kb, Vtb, AOb);
  gemm_wo<<<256, 512, 0, stream>>>(AOb, wob, out);
}

// Round 16
// 113.153 us; speedup vs baseline: 1.1625x; 1.1625x over previous
//
#include <hip/hip_runtime.h>
#include <hip/hip_bf16.h>
#include <math.h>

#define SEQ 2048
#define NH  16
#define DKH 64
#define DM  1024
#define MR  4096   // BATCH*SEQ

using bf16x8 = __attribute__((ext_vector_type(8))) short;
using f32x4  = __attribute__((ext_vector_type(4))) float;
using f32x16 = __attribute__((ext_vector_type(16))) float;

__device__ __forceinline__ ushort f2b(float f) {
  unsigned u = __float_as_uint(f);
  return (ushort)((u + 0x7fffu + ((u >> 16) & 1u)) >> 16);
}

__device__ __forceinline__ float exp2_fast(float x) {
  float r; asm("v_exp_f32 %0, %1" : "=v"(r) : "v"(x)); return r;
}

// packed bf16 pair via compiler intrinsic (correct hazards/scheduling)
__device__ __forceinline__ unsigned cvt_pk(float lo, float hi) {
  __hip_bfloat162 h = __float22bfloat162_rn(float2{lo, hi});
  return *reinterpret_cast<unsigned*>(&h);
}

// cross-half (lane ^ 32) reductions via the permlane32_swap builtin
__device__ __forceinline__ float xhalf_max(float x) {
  auto r = __builtin_amdgcn_permlane32_swap(__float_as_uint(x), __float_as_uint(x), false, false);
  return fmaxf(__uint_as_float(r[0]), __uint_as_float(r[1]));
}
__device__ __forceinline__ float xhalf_add(float x) {
  auto r = __builtin_amdgcn_permlane32_swap(__float_as_uint(x), __float_as_uint(x), false, false);
  return __uint_as_float(r[0]) + __uint_as_float(r[1]);
}

__device__ __forceinline__ void gll16(const void* g, void* l) {
  __builtin_amdgcn_global_load_lds(
      (const __attribute__((address_space(1))) void*)g,
      (__attribute__((address_space(3))) void*)l, 16, 0, 0);
}

// ---------------------------------------------------------------------------
// fp32 -> bf16 conversion of x and the 4 weight matrices (one launch)
// ---------------------------------------------------------------------------
__global__ __launch_bounds__(256) void cvt_all(
    const float* __restrict__ x,  const float* __restrict__ wq,
    const float* __restrict__ wk, const float* __restrict__ wv,
    const float* __restrict__ wo,
    ushort* __restrict__ xb,  ushort* __restrict__ wqb, ushort* __restrict__ wkb,
    ushort* __restrict__ wvb, ushort* __restrict__ wob)
{
  size_t e = ((size_t)blockIdx.x * 256 + threadIdx.x) * 4;
  const float* s; ushort* d; size_t off;
  if      (e < 4194304) { s = x;  d = xb;  off = e; }
  else if (e < 5242880) { s = wq; d = wqb; off = e - 4194304; }
  else if (e < 6291456) { s = wk; d = wkb; off = e - 5242880; }
  else if (e < 7340032) { s = wv; d = wvb; off = e - 6291456; }
  else                  { s = wo; d = wob; off = e - 7340032; }
  float4 f = *(const float4*)(s + off);
  ushort4 o4 = { f2b(f.x), f2b(f.y), f2b(f.z), f2b(f.w) };
  *(ushort4*)(d + off) = o4;
}

// ---------------------------------------------------------------------------
// Fused QKV projection (unchanged; Q pre-scale 0.125*log2(e)).
// ---------------------------------------------------------------------------
__global__ __launch_bounds__(512) void gemm_qkv(
    const ushort* __restrict__ X,
    const ushort* __restrict__ Wq, const ushort* __restrict__ Wk, const ushort* __restrict__ Wv,
    ushort* __restrict__ Q, ushort* __restrict__ K, ushort* __restrict__ Vt,
    const int* __restrict__ pos)
{
  __shared__ __align__(16) char As[2][16384];
  __shared__ __align__(16) char Bs[2][16384];

  const int id  = blockIdx.x;          // 768 blocks
  const int xcd = id & 7;
  const int i   = id >> 3;             // 0..95
  const int mt  = xcd * 4 + (i & 3);   // 0..31
  const int nt  = i >> 2;              // 0..23
  const int m0  = mt * 128;
  const int nG  = nt * 128;
  const int z   = nG >> 10;            // 0:Q 1:K 2:V
  const int n0  = nG & 1023;
  const ushort* W = (z == 0) ? Wq : (z == 1) ? Wk : Wv;

  const int tid  = threadIdx.x;
  const int lane = tid & 63;
  const int w    = tid >> 6;           // 0..7
  const int wm   = (w >> 2) * 64;
  const int wn   = (w & 3) * 32;
  const int li   = lane & 15;
  const int g    = lane >> 4;

  f32x4 acc[4][2] = {};

  auto stage = [&](int t, int buf) {
    const int k0 = t * 64;
    #pragma unroll
    for (int it = 0; it < 2; ++it) {
      const int L  = w * 2048 + it * 1024 + lane * 16;
      const int r  = L >> 7;
      const int sc = ((L >> 4) & 7) ^ (r & 7);
      gll16(X + (size_t)(m0 + r) * DM + k0 + sc * 8, &As[buf][w * 2048 + it * 1024]);
      gll16(W + (size_t)(n0 + r) * DM + k0 + sc * 8, &Bs[buf][w * 2048 + it * 1024]);
    }
  };

  auto compute = [&](int buf) {
    #pragma unroll
    for (int ks = 0; ks < 2; ++ks) {
      bf16x8 af[4], bfr[2];
      #pragma unroll
      for (int mf = 0; mf < 4; ++mf) {
        const int row = wm + mf * 16 + li;
        af[mf] = *(const bf16x8*)(&As[buf][row * 128 + (((ks * 4 + g) ^ (row & 7)) << 4)]);
      }
      #pragma unroll
      for (int nf = 0; nf < 2; ++nf) {
        const int row = wn + nf * 16 + li;
        bfr[nf] = *(const bf16x8*)(&Bs[buf][row * 128 + (((ks * 4 + g) ^ (row & 7)) << 4)]);
      }
      #pragma unroll
      for (int mf = 0; mf < 4; ++mf)
        #pragma unroll
        for (int nf = 0; nf < 2; ++nf)
          acc[mf][nf] = __builtin_amdgcn_mfma_f32_16x16x32_bf16(af[mf], bfr[nf], acc[mf][nf], 0, 0, 0);
    }
  };

  stage(0, 0);
  for (int t = 0; t < 16; ++t) {
    if (t < 15) {
      stage(t + 1, (t + 1) & 1);
      __builtin_amdgcn_sched_barrier(0);
      asm volatile("s_waitcnt vmcnt(4)" ::: "memory");
    } else {
      asm volatile("s_waitcnt vmcnt(0)" ::: "memory");
    }
    __builtin_amdgcn_s_barrier();
    __builtin_amdgcn_sched_barrier(0);
    compute(t & 1);
    __builtin_amdgcn_sched_barrier(0);
    __builtin_amdgcn_s_barrier();
  }

  #pragma unroll
  for (int nf = 0; nf < 2; ++nf) {
    const int n = n0 + wn + nf * 16 + li;
    const int h = n >> 6;
    const int d = n & 63;
    if (z == 2) {
      #pragma unroll
      for (int mf = 0; mf < 4; ++mf) {
        const int m  = m0 + wm + mf * 16 + g * 4;
        const int b  = m >> 11;
        const int s2 = m & (SEQ - 1);
        ushort4 pk = { f2b(acc[mf][nf][0]), f2b(acc[mf][nf][1]),
                       f2b(acc[mf][nf][2]), f2b(acc[mf][nf][3]) };
        *(ushort4*)(Vt + (((size_t)b * NH + h) * DKH + d) * SEQ + s2) = pk;
      }
    } else {
      ushort* DST = (z == 0) ? Q : K;
      const float freq = __expf(-(float)(d >> 1) * 0.2878231366242557f);
      #pragma unroll
      for (int mf = 0; mf < 4; ++mf) {
        #pragma unroll
        for (int r = 0; r < 4; ++r) {
          const int m  = m0 + wm + mf * 16 + g * 4 + r;
          const int b  = m >> 11;
          const int s2 = m & (SEQ - 1);
          const float ang = (float)pos[s2] * freq;
          float sn, cs;
          __sincosf(ang, &sn, &cs);
          const float v1 = acc[mf][nf][r];
          const float v2 = __shfl_xor(v1, 1);
          float ov = (d & 1) ? (v2 * sn + v1 * cs)
                             : (v1 * cs - v2 * sn);
          if (z == 0) ov *= 0.1803368801111204f;   // 0.125 * log2(e)
          DST[(((size_t)b * NH + h) * SEQ + s2) * DKH + d] = f2b(ov);
        }
      }
    }
  }
}

// ---------------------------------------------------------------------------
// Wo projection (unchanged).
// ---------------------------------------------------------------------------
__global__ __launch_bounds__(512) void gemm_wo(
    const ushort* __restrict__ A, const ushort* __restrict__ W,
    float* __restrict__ out)
{
  __shared__ __align__(16) char As[2][16384];
  __shared__ __align__(16) char Bs[2][16384];

  const int id  = blockIdx.x;          // 256 blocks
  const int xcd = id & 7;
  const int i   = id >> 3;
  const int mt  = xcd * 4 + (i & 3);
  const int nt  = i >> 2;
  const int m0  = mt * 128;
  const int n0  = nt * 128;

  const int tid  = threadIdx.x;
  const int lane = tid & 63;
  const int w    = tid >> 6;
  const int wm   = (w >> 2) * 64;
  const int wn   = (w & 3) * 32;
  const int li   = lane & 15;
  const int g    = lane >> 4;

  f32x4 acc[4][2] = {};

  auto stage = [&](int t, int buf) {
    const int k0 = t * 64;
    #pragma unroll
    for (int it = 0; it < 2; ++it) {
      const int L  = w * 2048 + it * 1024 + lane * 16;
      const int r  = L >> 7;
      const int sc = ((L >> 4) & 7) ^ (r & 7);
      gll16(A + (size_t)(m0 + r) * DM + k0 + sc * 8, &As[buf][w * 2048 + it * 1024]);
      gll16(W + (size_t)(n0 + r) * DM + k0 + sc * 8, &Bs[buf][w * 2048 + it * 1024]);
    }
  };

  auto compute = [&](int buf) {
    #pragma unroll
    for (int ks = 0; ks < 2; ++ks) {
      bf16x8 af[4], bfr[2];
      #pragma unroll
      for (int mf = 0; mf < 4; ++mf) {
        const int row = wm + mf * 16 + li;
        af[mf] = *(const bf16x8*)(&As[buf][row * 128 + (((ks * 4 + g) ^ (row & 7)) << 4)]);
      }
      #pragma unroll
      for (int nf = 0; nf < 2; ++nf) {
        const int row = wn + nf * 16 + li;
        bfr[nf] = *(const bf16x8*)(&Bs[buf][row * 128 + (((ks * 4 + g) ^ (row & 7)) << 4)]);
      }
      #pragma unroll
      for (int mf = 0; mf < 4; ++mf)
        #pragma unroll
        for (int nf = 0; nf < 2; ++nf)
          acc[mf][nf] = __builtin_amdgcn_mfma_f32_16x16x32_bf16(af[mf], bfr[nf], acc[mf][nf], 0, 0, 0);
    }
  };

  stage(0, 0);
  for (int t = 0; t < 16; ++t) {
    if (t < 15) {
      stage(t + 1, (t + 1) & 1);
      __builtin_amdgcn_sched_barrier(0);
      asm volatile("s_waitcnt vmcnt(4)" ::: "memory");
    } else {
      asm volatile("s_waitcnt vmcnt(0)" ::: "memory");
    }
    __builtin_amdgcn_s_barrier();
    __builtin_amdgcn_sched_barrier(0);
    compute(t & 1);
    __builtin_amdgcn_sched_barrier(0);
    __builtin_amdgcn_s_barrier();
  }

  #pragma unroll
  for (int nf = 0; nf < 2; ++nf)
    #pragma unroll
    for (int mf = 0; mf < 4; ++mf)
      #pragma unroll
      for (int r = 0; r < 4; ++r)
        out[(size_t)(m0 + wm + mf * 16 + g * 4 + r) * DM + n0 + wn + nf * 16 + li] = acc[mf][nf][r];
}

// ---------------------------------------------------------------------------
// Causal flash attention — ONE WAVE PER BLOCK, ZERO BARRIERS.
// r11-verified 32x32x16 compute: swapped QK^T (mfma(K,Q)) with q in the
// lane column, fully in-register softmax (permlane32 cross-half reduce),
// P -> PV B-operand via cvt_pk + permlane32_swap (no P-LDS).
// Each wave owns 32 q-rows and a private 16KB K/V LDS slice; the only
// sync is vmcnt(0) (same-wave gll16 -> ds_read visibility). 2048 blocks
// (32 bh x 64 units), 10 blocks/CU LDS capacity -> 8 fully independent
// waves/CU resident; the dur*VALUBusy ~ 22us-VALU law says independence
// is the lever. Heavy-first LPT, heads pinned per XCD.
// ---------------------------------------------------------------------------
__global__ __launch_bounds__(64) void attn(
    const ushort* __restrict__ Q, const ushort* __restrict__ K,
    const ushort* __restrict__ Vt, ushort* __restrict__ AO)
{
  __shared__ __align__(16) char Ks[8192];   // 64 kv-rows x 128B, swizzled
  __shared__ __align__(16) char Vs[8192];   // 64 d-rows x 128B, swizzled

  const int lane = threadIdx.x & 63;
  const int lq   = lane & 31;          // q column within 32
  const int hi   = lane >> 5;

  const int bx  = blockIdx.x;          // 2048 blocks
  const int xcd = bx & 7;
  const int i   = bx >> 3;             // 0..255
  const int uu  = 63 - (i >> 2);       // 32-row unit, heavy first
  const int bh  = (i & 3) * 8 + xcd;   // heads pinned per XCD
  const int q0w = uu * 32;
  const int ntr = (uu >> 1) + 1;       // kv64 tiles needed
  const int q_abs = q0w + lq;

  const ushort* Qb = Q  + (size_t)bh * SEQ * DKH;
  const ushort* Kb = K  + (size_t)bh * SEQ * DKH;
  const ushort* Vb = Vt + (size_t)bh * DKH * SEQ;

  // Q B-frags (col q = lq, k = d = db*16 + hi*8 + e)
  bf16x8 qf[4];
  #pragma unroll
  for (int db = 0; db < 4; ++db)
    qf[db] = *(const bf16x8*)(Qb + (size_t)(q0w + lq) * DKH + db * 16 + hi * 8);

  f32x16 o0 = {}, o1 = {};             // O^T: d-rows [0,32) / [32,64), col q
  float m_ = -INFINITY, l_ = 0.f;

  auto stage = [&](int kt) {           // 16KB: 8 K-loads + 8 V-loads
    const int k0 = kt * 64;
    #pragma unroll
    for (int it = 0; it < 8; ++it) {
      const int L  = it * 1024 + lane * 16;
      const int r  = L >> 7;
      const int sc = ((L >> 4) & 7) ^ (r & 7);
      gll16(Kb + (size_t)(k0 + r) * DKH + sc * 8, Ks + it * 1024);
      gll16(Vb + (size_t)r * SEQ + k0 + sc * 8,   Vs + it * 1024);
    }
  };

// PV step for one 16-kv sub: build P^T B-frag from own regs + 2 permlane swaps
#define PVSTEP(P, S4) do {                                                   \
    unsigned A0 = cvt_pk((P)[((S4)&1)*8 + 0], (P)[((S4)&1)*8 + 1]);          \
    unsigned A1 = cvt_pk((P)[((S4)&1)*8 + 2], (P)[((S4)&1)*8 + 3]);          \
    unsigned B0 = cvt_pk((P)[((S4)&1)*8 + 4], (P)[((S4)&1)*8 + 5]);          \
    unsigned B1 = cvt_pk((P)[((S4)&1)*8 + 6], (P)[((S4)&1)*8 + 7]);          \
    auto r0 = __builtin_amdgcn_permlane32_swap(A0, B0, false, false);        \
    auto r1 = __builtin_amdgcn_permlane32_swap(A1, B1, false, false);        \
    int4 ti = { (int)r0[0], (int)r1[0], (int)r0[1], (int)r1[1] };            \
    bf16x8 pf = *(bf16x8*)&ti;                                               \
    const int uv = (S4) * 2 + hi;                                            \
    bf16x8 va = *(const bf16x8*)(Vs + lq * 128      + ((uv ^ (lq & 7)) << 4)); \
    bf16x8 vb = *(const bf16x8*)(Vs + (32+lq) * 128 + ((uv ^ (lq & 7)) << 4)); \
    o0 = __builtin_amdgcn_mfma_f32_32x32x16_bf16(va, pf, o0, 0, 0, 0);       \
    o1 = __builtin_amdgcn_mfma_f32_32x32x16_bf16(vb, pf, o1, 0, 0, 0);       \
  } while (0)

  auto computeT = [&](int t, bool diag) {
    const int k0 = t * 64;

    // S^T = K Q^T : st0 = kv [0,32), st1 = kv [32,64); col q = lq
    f32x16 st0 = {}, st1 = {};
    __builtin_amdgcn_s_setprio(1);
    #pragma unroll
    for (int db = 0; db < 4; ++db) {
      const int uk = db * 2 + hi;
      bf16x8 ka = *(const bf16x8*)(Ks + lq * 128      + ((uk ^ (lq & 7)) << 4));
      bf16x8 kb = *(const bf16x8*)(Ks + (32+lq) * 128 + ((uk ^ (lq & 7)) << 4));
      st0 = __builtin_amdgcn_mfma_f32_32x32x16_bf16(ka, qf[db], st0, 0, 0, 0);
      st1 = __builtin_amdgcn_mfma_f32_32x32x16_bf16(kb, qf[db], st1, 0, 0, 0);
    }
    __builtin_amdgcn_s_setprio(0);

    if (diag) {
      #pragma unroll
      for (int reg = 0; reg < 16; ++reg) {
        const int kvr = (reg & 3) + 8 * (reg >> 2) + 4 * hi;
        if (k0 + kvr > q_abs)      st0[reg] = -1e30f;
        if (k0 + 32 + kvr > q_abs) st1[reg] = -1e30f;
      }
    }

    // in-register row max (row q = lane's column)
    float mx = st0[0];
    #pragma unroll
    for (int r = 1; r < 16; ++r) mx = fmaxf(mx, st0[r]);
    #pragma unroll
    for (int r = 0; r < 16; ++r) mx = fmaxf(mx, st1[r]);
    mx = xhalf_max(mx);

    const bool resc = !__all(mx - m_ <= 8.0f);   // defer-max (log2 domain)
    float al = 1.0f;
    if (resc) { const float nm = fmaxf(m_, mx); al = exp2_fast(m_ - nm); m_ = nm; }

    float rs = 0.f;
    #pragma unroll
    for (int r = 0; r < 16; ++r) { st0[r] = exp2_fast(st0[r] - m_); rs += st0[r]; }
    #pragma unroll
    for (int r = 0; r < 16; ++r) { st1[r] = exp2_fast(st1[r] - m_); rs += st1[r]; }
    rs = xhalf_add(rs);

    if (resc) {
      l_ = l_ * al + rs;
      #pragma unroll
      for (int r = 0; r < 16; ++r) { o0[r] *= al; o1[r] *= al; }
    } else {
      l_ += rs;
    }

    // O^T += V^T P^T
    __builtin_amdgcn_s_setprio(1);
    PVSTEP(st0, 0);
    PVSTEP(st0, 1);
    PVSTEP(st1, 2);
    PVSTEP(st1, 3);
    __builtin_amdgcn_s_setprio(0);
  };

  // ---- barrier-free loop: vmcnt(0) is the only synchronization ----
  for (int t = 0; t < ntr; ++t) {
    __builtin_amdgcn_sched_barrier(0);       // keep prior ds_reads before restage
    stage(t);
    __builtin_amdgcn_sched_barrier(0);
    asm volatile("s_waitcnt vmcnt(0)" ::: "memory");
    computeT(t, t == ntr - 1);
  }

  // epilogue: lane-local 1/l; d-contiguous packed stores (q = lane's row)
  const float inv = 1.0f / l_;
  const int b = bh >> 4, h = bh & 15;
  ushort* dst = AO + ((size_t)b * SEQ + q_abs) * DM + h * DKH;

#define STORE16(OV, DSUB) do {                                               \
    _Pragma("unroll")                                                        \
    for (int rq = 0; rq < 4; ++rq) {                                         \
      const int d0 = (DSUB) * 32 + rq * 8 + hi * 4;                          \
      uint2 pk = { cvt_pk((OV)[rq*4+0] * inv, (OV)[rq*4+1] * inv),           \
                   cvt_pk((OV)[rq*4+2] * inv, (OV)[rq*4+3] * inv) };         \
      *(uint2*)(dst + d0) = pk;                                              \
    }                                                                        \
  } while (0)

  STORE16(o0, 0);
  STORE16(o1, 1);
}

// ---------------------------------------------------------------------------
extern "C" void kernel_launch(void* const* d_in, const int* in_sizes, int n_in,
                              void* d_out, int out_size, void* d_ws, size_t ws_size,
                              hipStream_t stream)
{
  const float* x   = (const float*)d_in[0];
  const int*   pos = (const int*)  d_in[1];
  const float* Wq  = (const float*)d_in[2];
  const float* Wk  = (const float*)d_in[3];
  const float* Wv  = (const float*)d_in[4];
  const float* Wo  = (const float*)d_in[5];
  float* out = (float*)d_out;

  ushort* ws  = (ushort*)d_ws;
  ushort* xb  = ws;                    // 4M
  ushort* wqb = xb  + 4194304;         // 1M each
  ushort* wkb = wqb + 1048576;
  ushort* wvb = wkb + 1048576;
  ushort* wob = wvb + 1048576;
  ushort* Qb  = wob + 1048576;         // 4M each
  ushort* Kb  = Qb  + 4194304;
  ushort* Vtb = Kb  + 4194304;
  ushort* AOb = Vtb + 4194304;

  cvt_all<<<8192, 256, 0, stream>>>(x, Wq, Wk, Wv, Wo, xb, wqb, wkb, wvb, wob);
  gemm_qkv<<<768, 512, 0, stream>>>(xb, wqb, wkb, wvb, Qb, Kb, Vtb, pos);
  attn<<<2048, 64, 0, stream>>>(Qb, Kb, Vtb, AOb);
  gemm_wo<<<256, 512, 0, stream>>>(AOb, wob, out);
}

// Round 17
// 110.874 us; speedup vs baseline: 1.1864x; 1.0206x over previous
//
#include <hip/hip_runtime.h>
#include <hip/hip_bf16.h>
#include <math.h>

#define SEQ 2048
#define NH  16
#define DKH 64
#define DM  1024
#define MR  4096   // BATCH*SEQ

using bf16x8 = __attribute__((ext_vector_type(8))) short;
using f32x4  = __attribute__((ext_vector_type(4))) float;
using f32x16 = __attribute__((ext_vector_type(16))) float;

__device__ __forceinline__ ushort f2b(float f) {
  unsigned u = __float_as_uint(f);
  return (ushort)((u + 0x7fffu + ((u >> 16) & 1u)) >> 16);
}

__device__ __forceinline__ float exp2_fast(float x) {
  float r; asm("v_exp_f32 %0, %1" : "=v"(r) : "v"(x)); return r;
}

// packed bf16 pair via compiler intrinsic (correct hazards/scheduling)
__device__ __forceinline__ unsigned cvt_pk(float lo, float hi) {
  __hip_bfloat162 h = __float22bfloat162_rn(float2{lo, hi});
  return *reinterpret_cast<unsigned*>(&h);
}

// cross-half (lane ^ 32) reductions via the permlane32_swap builtin
__device__ __forceinline__ float xhalf_max(float x) {
  auto r = __builtin_amdgcn_permlane32_swap(__float_as_uint(x), __float_as_uint(x), false, false);
  return fmaxf(__uint_as_float(r[0]), __uint_as_float(r[1]));
}
__device__ __forceinline__ float xhalf_add(float x) {
  auto r = __builtin_amdgcn_permlane32_swap(__float_as_uint(x), __float_as_uint(x), false, false);
  return __uint_as_float(r[0]) + __uint_as_float(r[1]);
}

__device__ __forceinline__ void gll16(const void* g, void* l) {
  __builtin_amdgcn_global_load_lds(
      (const __attribute__((address_space(1))) void*)g,
      (__attribute__((address_space(3))) void*)l, 16, 0, 0);
}

// ---------------------------------------------------------------------------
// fp32 -> bf16 conversion of x and the 4 weight matrices (one launch)
// ---------------------------------------------------------------------------
__global__ __launch_bounds__(256) void cvt_all(
    const float* __restrict__ x,  const float* __restrict__ wq,
    const float* __restrict__ wk, const float* __restrict__ wv,
    const float* __restrict__ wo,
    ushort* __restrict__ xb,  ushort* __restrict__ wqb, ushort* __restrict__ wkb,
    ushort* __restrict__ wvb, ushort* __restrict__ wob)
{
  size_t e = ((size_t)blockIdx.x * 256 + threadIdx.x) * 4;
  const float* s; ushort* d; size_t off;
  if      (e < 4194304) { s = x;  d = xb;  off = e; }
  else if (e < 5242880) { s = wq; d = wqb; off = e - 4194304; }
  else if (e < 6291456) { s = wk; d = wkb; off = e - 5242880; }
  else if (e < 7340032) { s = wv; d = wvb; off = e - 6291456; }
  else                  { s = wo; d = wob; off = e - 7340032; }
  float4 f = *(const float4*)(s + off);
  ushort4 o4 = { f2b(f.x), f2b(f.y), f2b(f.z), f2b(f.w) };
  *(ushort4*)(d + off) = o4;
}

// ---------------------------------------------------------------------------
// Fused QKV projection (unchanged; Q pre-scale 0.125*log2(e)).
// ---------------------------------------------------------------------------
__global__ __launch_bounds__(512) void gemm_qkv(
    const ushort* __restrict__ X,
    const ushort* __restrict__ Wq, const ushort* __restrict__ Wk, const ushort* __restrict__ Wv,
    ushort* __restrict__ Q, ushort* __restrict__ K, ushort* __restrict__ Vt,
    const int* __restrict__ pos)
{
  __shared__ __align__(16) char As[2][16384];
  __shared__ __align__(16) char Bs[2][16384];

  const int id  = blockIdx.x;          // 768 blocks
  const int xcd = id & 7;
  const int i   = id >> 3;             // 0..95
  const int mt  = xcd * 4 + (i & 3);   // 0..31
  const int nt  = i >> 2;              // 0..23
  const int m0  = mt * 128;
  const int nG  = nt * 128;
  const int z   = nG >> 10;            // 0:Q 1:K 2:V
  const int n0  = nG & 1023;
  const ushort* W = (z == 0) ? Wq : (z == 1) ? Wk : Wv;

  const int tid  = threadIdx.x;
  const int lane = tid & 63;
  const int w    = tid >> 6;           // 0..7
  const int wm   = (w >> 2) * 64;
  const int wn   = (w & 3) * 32;
  const int li   = lane & 15;
  const int g    = lane >> 4;

  f32x4 acc[4][2] = {};

  auto stage = [&](int t, int buf) {
    const int k0 = t * 64;
    #pragma unroll
    for (int it = 0; it < 2; ++it) {
      const int L  = w * 2048 + it * 1024 + lane * 16;
      const int r  = L >> 7;
      const int sc = ((L >> 4) & 7) ^ (r & 7);
      gll16(X + (size_t)(m0 + r) * DM + k0 + sc * 8, &As[buf][w * 2048 + it * 1024]);
      gll16(W + (size_t)(n0 + r) * DM + k0 + sc * 8, &Bs[buf][w * 2048 + it * 1024]);
    }
  };

  auto compute = [&](int buf) {
    #pragma unroll
    for (int ks = 0; ks < 2; ++ks) {
      bf16x8 af[4], bfr[2];
      #pragma unroll
      for (int mf = 0; mf < 4; ++mf) {
        const int row = wm + mf * 16 + li;
        af[mf] = *(const bf16x8*)(&As[buf][row * 128 + (((ks * 4 + g) ^ (row & 7)) << 4)]);
      }
      #pragma unroll
      for (int nf = 0; nf < 2; ++nf) {
        const int row = wn + nf * 16 + li;
        bfr[nf] = *(const bf16x8*)(&Bs[buf][row * 128 + (((ks * 4 + g) ^ (row & 7)) << 4)]);
      }
      #pragma unroll
      for (int mf = 0; mf < 4; ++mf)
        #pragma unroll
        for (int nf = 0; nf < 2; ++nf)
          acc[mf][nf] = __builtin_amdgcn_mfma_f32_16x16x32_bf16(af[mf], bfr[nf], acc[mf][nf], 0, 0, 0);
    }
  };

  stage(0, 0);
  for (int t = 0; t < 16; ++t) {
    if (t < 15) {
      stage(t + 1, (t + 1) & 1);
      __builtin_amdgcn_sched_barrier(0);
      asm volatile("s_waitcnt vmcnt(4)" ::: "memory");
    } else {
      asm volatile("s_waitcnt vmcnt(0)" ::: "memory");
    }
    __builtin_amdgcn_s_barrier();
    __builtin_amdgcn_sched_barrier(0);
    compute(t & 1);
    __builtin_amdgcn_sched_barrier(0);
    __builtin_amdgcn_s_barrier();
  }

  #pragma unroll
  for (int nf = 0; nf < 2; ++nf) {
    const int n = n0 + wn + nf * 16 + li;
    const int h = n >> 6;
    const int d = n & 63;
    if (z == 2) {
      #pragma unroll
      for (int mf = 0; mf < 4; ++mf) {
        const int m  = m0 + wm + mf * 16 + g * 4;
        const int b  = m >> 11;
        const int s2 = m & (SEQ - 1);
        ushort4 pk = { f2b(acc[mf][nf][0]), f2b(acc[mf][nf][1]),
                       f2b(acc[mf][nf][2]), f2b(acc[mf][nf][3]) };
        *(ushort4*)(Vt + (((size_t)b * NH + h) * DKH + d) * SEQ + s2) = pk;
      }
    } else {
      ushort* DST = (z == 0) ? Q : K;
      const float freq = __expf(-(float)(d >> 1) * 0.2878231366242557f);
      #pragma unroll
      for (int mf = 0; mf < 4; ++mf) {
        #pragma unroll
        for (int r = 0; r < 4; ++r) {
          const int m  = m0 + wm + mf * 16 + g * 4 + r;
          const int b  = m >> 11;
          const int s2 = m & (SEQ - 1);
          const float ang = (float)pos[s2] * freq;
          float sn, cs;
          __sincosf(ang, &sn, &cs);
          const float v1 = acc[mf][nf][r];
          const float v2 = __shfl_xor(v1, 1);
          float ov = (d & 1) ? (v2 * sn + v1 * cs)
                             : (v1 * cs - v2 * sn);
          if (z == 0) ov *= 0.1803368801111204f;   // 0.125 * log2(e)
          DST[(((size_t)b * NH + h) * SEQ + s2) * DKH + d] = f2b(ov);
        }
      }
    }
  }
}

// ---------------------------------------------------------------------------
// Wo projection (unchanged).
// ---------------------------------------------------------------------------
__global__ __launch_bounds__(512) void gemm_wo(
    const ushort* __restrict__ A, const ushort* __restrict__ W,
    float* __restrict__ out)
{
  __shared__ __align__(16) char As[2][16384];
  __shared__ __align__(16) char Bs[2][16384];

  const int id  = blockIdx.x;          // 256 blocks
  const int xcd = id & 7;
  const int i   = id >> 3;
  const int mt  = xcd * 4 + (i & 3);
  const int nt  = i >> 2;
  const int m0  = mt * 128;
  const int n0  = nt * 128;

  const int tid  = threadIdx.x;
  const int lane = tid & 63;
  const int w    = tid >> 6;
  const int wm   = (w >> 2) * 64;
  const int wn   = (w & 3) * 32;
  const int li   = lane & 15;
  const int g    = lane >> 4;

  f32x4 acc[4][2] = {};

  auto stage = [&](int t, int buf) {
    const int k0 = t * 64;
    #pragma unroll
    for (int it = 0; it < 2; ++it) {
      const int L  = w * 2048 + it * 1024 + lane * 16;
      const int r  = L >> 7;
      const int sc = ((L >> 4) & 7) ^ (r & 7);
      gll16(A + (size_t)(m0 + r) * DM + k0 + sc * 8, &As[buf][w * 2048 + it * 1024]);
      gll16(W + (size_t)(n0 + r) * DM + k0 + sc * 8, &Bs[buf][w * 2048 + it * 1024]);
    }
  };

  auto compute = [&](int buf) {
    #pragma unroll
    for (int ks = 0; ks < 2; ++ks) {
      bf16x8 af[4], bfr[2];
      #pragma unroll
      for (int mf = 0; mf < 4; ++mf) {
        const int row = wm + mf * 16 + li;
        af[mf] = *(const bf16x8*)(&As[buf][row * 128 + (((ks * 4 + g) ^ (row & 7)) << 4)]);
      }
      #pragma unroll
      for (int nf = 0; nf < 2; ++nf) {
        const int row = wn + nf * 16 + li;
        bfr[nf] = *(const bf16x8*)(&Bs[buf][row * 128 + (((ks * 4 + g) ^ (row & 7)) << 4)]);
      }
      #pragma unroll
      for (int mf = 0; mf < 4; ++mf)
        #pragma unroll
        for (int nf = 0; nf < 2; ++nf)
          acc[mf][nf] = __builtin_amdgcn_mfma_f32_16x16x32_bf16(af[mf], bfr[nf], acc[mf][nf], 0, 0, 0);
    }
  };

  stage(0, 0);
  for (int t = 0; t < 16; ++t) {
    if (t < 15) {
      stage(t + 1, (t + 1) & 1);
      __builtin_amdgcn_sched_barrier(0);
      asm volatile("s_waitcnt vmcnt(4)" ::: "memory");
    } else {
      asm volatile("s_waitcnt vmcnt(0)" ::: "memory");
    }
    __builtin_amdgcn_s_barrier();
    __builtin_amdgcn_sched_barrier(0);
    compute(t & 1);
    __builtin_amdgcn_sched_barrier(0);
    __builtin_amdgcn_s_barrier();
  }

  #pragma unroll
  for (int nf = 0; nf < 2; ++nf)
    #pragma unroll
    for (int mf = 0; mf < 4; ++mf)
      #pragma unroll
      for (int r = 0; r < 4; ++r)
        out[(size_t)(m0 + wm + mf * 16 + g * 4 + r) * DM + n0 + wn + nf * 16 + li] = acc[mf][nf][r];
}

// ---------------------------------------------------------------------------
// Causal flash attention — SPLIT-KV x4 with INDEPENDENT waves.
// Block = 4 waves, one (bh, 32-q-row unit). Wave w handles kv64 tiles
// t = w, w+4, ... < ntr, each with a PRIVATE 16KB LDS slice and the r16
// barrier-free loop (own gll16 + vmcnt(0) only). Heaviest chain: 32 -> 8
// trips. ONE final __syncthreads: waves 1-3 dump (O^T, m, l) into their
// own idle staging slices ([r][lane] conflict-free layout); wave 0 merges
// lane-locally (q = lane column; no shuffles) and writes AO.
// r16's verified 32x32 in-register compute byte-identical.
// ---------------------------------------------------------------------------
__global__ __launch_bounds__(256) void attn(
    const ushort* __restrict__ Q, const ushort* __restrict__ K,
    const ushort* __restrict__ Vt, ushort* __restrict__ AO)
{
  __shared__ __align__(16) char smem[65536];   // 4 waves x 16KB slices

  const int tid  = threadIdx.x;
  const int lane = tid & 63;
  const int w    = tid >> 6;           // 0..3
  const int lq   = lane & 31;          // q column within 32
  const int hi   = lane >> 5;

  const int bx  = blockIdx.x;          // 2048 blocks
  const int xcd = bx & 7;
  const int i   = bx >> 3;             // 0..255
  const int uu  = 63 - (i >> 2);       // 32-row unit, heavy first
  const int bh  = (i & 3) * 8 + xcd;   // heads pinned per XCD
  const int q0w = uu * 32;
  const int ntr = (uu >> 1) + 1;       // kv64 tiles needed
  const int q_abs = q0w + lq;

  const ushort* Qb = Q  + (size_t)bh * SEQ * DKH;
  const ushort* Kb = K  + (size_t)bh * SEQ * DKH;
  const ushort* Vb = Vt + (size_t)bh * DKH * SEQ;

  char* Ks = smem + w * 16384;         // private slice: K 8KB
  char* Vs = Ks + 8192;                //                V 8KB

  // Q B-frags (col q = lq, k = d = db*16 + hi*8 + e) — same for all waves
  bf16x8 qf[4];
  #pragma unroll
  for (int db = 0; db < 4; ++db)
    qf[db] = *(const bf16x8*)(Qb + (size_t)(q0w + lq) * DKH + db * 16 + hi * 8);

  f32x16 o0 = {}, o1 = {};             // O^T: d-rows [0,32) / [32,64), col q
  float m_ = -INFINITY, l_ = 0.f;

  auto stage = [&](int kt) {           // 16KB into private slice
    const int k0 = kt * 64;
    #pragma unroll
    for (int it = 0; it < 8; ++it) {
      const int L  = it * 1024 + lane * 16;
      const int r  = L >> 7;
      const int sc = ((L >> 4) & 7) ^ (r & 7);
      gll16(Kb + (size_t)(k0 + r) * DKH + sc * 8, Ks + it * 1024);
      gll16(Vb + (size_t)r * SEQ + k0 + sc * 8,   Vs + it * 1024);
    }
  };

// PV step for one 16-kv sub: build P^T B-frag from own regs + 2 permlane swaps
#define PVSTEP(P, S4) do {                                                   \
    unsigned A0 = cvt_pk((P)[((S4)&1)*8 + 0], (P)[((S4)&1)*8 + 1]);          \
    unsigned A1 = cvt_pk((P)[((S4)&1)*8 + 2], (P)[((S4)&1)*8 + 3]);          \
    unsigned B0 = cvt_pk((P)[((S4)&1)*8 + 4], (P)[((S4)&1)*8 + 5]);          \
    unsigned B1 = cvt_pk((P)[((S4)&1)*8 + 6], (P)[((S4)&1)*8 + 7]);          \
    auto r0 = __builtin_amdgcn_permlane32_swap(A0, B0, false, false);        \
    auto r1 = __builtin_amdgcn_permlane32_swap(A1, B1, false, false);        \
    int4 ti = { (int)r0[0], (int)r1[0], (int)r0[1], (int)r1[1] };            \
    bf16x8 pf = *(bf16x8*)&ti;                                               \
    const int uv = (S4) * 2 + hi;                                            \
    bf16x8 va = *(const bf16x8*)(Vs + lq * 128      + ((uv ^ (lq & 7)) << 4)); \
    bf16x8 vb = *(const bf16x8*)(Vs + (32+lq) * 128 + ((uv ^ (lq & 7)) << 4)); \
    o0 = __builtin_amdgcn_mfma_f32_32x32x16_bf16(va, pf, o0, 0, 0, 0);       \
    o1 = __builtin_amdgcn_mfma_f32_32x32x16_bf16(vb, pf, o1, 0, 0, 0);       \
  } while (0)

  auto computeT = [&](int t, bool diag) {
    const int k0 = t * 64;

    f32x16 st0 = {}, st1 = {};
    __builtin_amdgcn_s_setprio(1);
    #pragma unroll
    for (int db = 0; db < 4; ++db) {
      const int uk = db * 2 + hi;
      bf16x8 ka = *(const bf16x8*)(Ks + lq * 128      + ((uk ^ (lq & 7)) << 4));
      bf16x8 kb = *(const bf16x8*)(Ks + (32+lq) * 128 + ((uk ^ (lq & 7)) << 4));
      st0 = __builtin_amdgcn_mfma_f32_32x32x16_bf16(ka, qf[db], st0, 0, 0, 0);
      st1 = __builtin_amdgcn_mfma_f32_32x32x16_bf16(kb, qf[db], st1, 0, 0, 0);
    }
    __builtin_amdgcn_s_setprio(0);

    if (diag) {
      #pragma unroll
      for (int reg = 0; reg < 16; ++reg) {
        const int kvr = (reg & 3) + 8 * (reg >> 2) + 4 * hi;
        if (k0 + kvr > q_abs)      st0[reg] = -1e30f;
        if (k0 + 32 + kvr > q_abs) st1[reg] = -1e30f;
      }
    }

    float mx = st0[0];
    #pragma unroll
    for (int r = 1; r < 16; ++r) mx = fmaxf(mx, st0[r]);
    #pragma unroll
    for (int r = 0; r < 16; ++r) mx = fmaxf(mx, st1[r]);
    mx = xhalf_max(mx);

    const bool resc = !__all(mx - m_ <= 8.0f);   // defer-max (log2 domain)
    float al = 1.0f;
    if (resc) { const float nm = fmaxf(m_, mx); al = exp2_fast(m_ - nm); m_ = nm; }

    float rs = 0.f;
    #pragma unroll
    for (int r = 0; r < 16; ++r) { st0[r] = exp2_fast(st0[r] - m_); rs += st0[r]; }
    #pragma unroll
    for (int r = 0; r < 16; ++r) { st1[r] = exp2_fast(st1[r] - m_); rs += st1[r]; }
    rs = xhalf_add(rs);

    if (resc) {
      l_ = l_ * al + rs;
      #pragma unroll
      for (int r = 0; r < 16; ++r) { o0[r] *= al; o1[r] *= al; }
    } else {
      l_ += rs;
    }

    __builtin_amdgcn_s_setprio(1);
    PVSTEP(st0, 0);
    PVSTEP(st0, 1);
    PVSTEP(st1, 2);
    PVSTEP(st1, 3);
    __builtin_amdgcn_s_setprio(0);
  };

  // ---- independent per-wave loop: vmcnt(0) is the only sync ----
  for (int t = w; t < ntr; t += 4) {
    __builtin_amdgcn_sched_barrier(0);       // prior ds_reads before restage
    stage(t);
    __builtin_amdgcn_sched_barrier(0);
    asm volatile("s_waitcnt vmcnt(0)" ::: "memory");
    computeT(t, t == ntr - 1);
  }

  // ---- merge: waves 1-3 dump into their own idle slices; wave 0 combines ----
  if (w != 0) {
    float* Om = (float*)(smem + w * 16384);        // [r][lane], conflict-free
    #pragma unroll
    for (int r = 0; r < 16; ++r) {
      Om[r * 64 + lane]        = o0[r];
      Om[(16 + r) * 64 + lane] = o1[r];
    }
    float* Ml = (float*)(smem + w * 16384 + 8192);
    Ml[lane * 2 + 0] = m_;
    Ml[lane * 2 + 1] = l_;
  }
  __syncthreads();
  if (w == 0) {
    float mw[3], lw[3];
    float ms = m_;
    #pragma unroll
    for (int j = 0; j < 3; ++j) {
      const float* Ml = (const float*)(smem + (j + 1) * 16384 + 8192);
      mw[j] = Ml[lane * 2 + 0];
      lw[j] = Ml[lane * 2 + 1];
      ms = fmaxf(ms, mw[j]);
    }
    const float s0 = exp2_fast(m_ - ms);
    float lt = l_ * s0;
    #pragma unroll
    for (int r = 0; r < 16; ++r) { o0[r] *= s0; o1[r] *= s0; }
    #pragma unroll
    for (int j = 0; j < 3; ++j) {
      const float sj = exp2_fast(mw[j] - ms);    // 2^(-inf)=0 for idle waves
      lt += lw[j] * sj;
      const float* Om = (const float*)(smem + (j + 1) * 16384);
      #pragma unroll
      for (int r = 0; r < 16; ++r) {
        o0[r] += Om[r * 64 + lane] * sj;
        o1[r] += Om[(16 + r) * 64 + lane] * sj;
      }
    }

    const float inv = 1.0f / lt;
    const int b = bh >> 4, h = bh & 15;
    ushort* dst = AO + ((size_t)b * SEQ + q_abs) * DM + h * DKH;

#define STORE16(OV, DSUB) do {                                               \
    _Pragma("unroll")                                                        \
    for (int rq = 0; rq < 4; ++rq) {                                         \
      const int d0 = (DSUB) * 32 + rq * 8 + hi * 4;                          \
      uint2 pk = { cvt_pk((OV)[rq*4+0] * inv, (OV)[rq*4+1] * inv),           \
                   cvt_pk((OV)[rq*4+2] * inv, (OV)[rq*4+3] * inv) };         \
      *(uint2*)(dst + d0) = pk;                                              \
    }                                                                        \
  } while (0)

    STORE16(o0, 0);
    STORE16(o1, 1);
  }
}

// ---------------------------------------------------------------------------
extern "C" void kernel_launch(void* const* d_in, const int* in_sizes, int n_in,
                              void* d_out, int out_size, void* d_ws, size_t ws_size,
                              hipStream_t stream)
{
  const float* x   = (const float*)d_in[0];
  const int*   pos = (const int*)  d_in[1];
  const float* Wq  = (const float*)d_in[2];
  const float* Wk  = (const float*)d_in[3];
  const float* Wv  = (const float*)d_in[4];
  const float* Wo  = (const float*)d_in[5];
  float* out = (float*)d_out;

  ushort* ws  = (ushort*)d_ws;
  ushort* xb  = ws;                    // 4M
  ushort* wqb = xb  + 4194304;         // 1M each
  ushort* wkb = wqb + 1048576;
  ushort* wvb = wkb + 1048576;
  ushort* wob = wvb + 1048576;
  ushort* Qb  = wob + 1048576;         // 4M each
  ushort* Kb  = Qb  + 4194304;
  ushort* Vtb = Kb  + 4194304;
  ushort* AOb = Vtb + 4194304;

  cvt_all<<<8192, 256, 0, stream>>>(x, Wq, Wk, Wv, Wo, xb, wqb, wkb, wvb, wob);
  gemm_qkv<<<768, 512, 0, stream>>>(xb, wqb, wkb, wvb, Qb, Kb, Vtb, pos);
  attn<<<2048, 256, 0, stream>>>(Qb, Kb, Vtb, AOb);
  gemm_wo<<<256, 512, 0, stream>>>(AOb, wob, out);
}